// Round 9
// baseline (234.781 us; speedup 1.0000x reference)
//
#include <hip/hip_runtime.h>

// ---------------------------------------------------------------------------
// AttentionFuse: out[b,d] = mean_s( softmax((x Wq + bq)(x Wk + bk)^T / 32) @ (x Wv + bv) )
// Algebra:
//   mean_s(attn @ V) = sum_t a[t] V[t,:]  =>  out = (a^T x) Wv + bv   (V GEMM gone)
//   S = x (Wq Wk^T) x^T  =>  y = x Mt^T, Mt = Wk Wq^T (2.1 GF)  =>  S = y x^T
//   bias: P[s,t] = exp(scale*S + c[t]),  c[t] = scale * x[t].u,  u = Wk bq
// R9: P stored as fp8 e4m3fn (ell from decoded values -> rows normalize
//   exactly; quant errors average over s AND t -> ~1e-5 added output error);
//   c fused into k_cvt_x; k_mm K-split x4 (256 blocks + fp32 atomic acc).
// GEMM core: R5 best-measured variant (~900 TF plateau, accepted).
// ---------------------------------------------------------------------------

using bf16x8 = __attribute__((ext_vector_type(8))) __bf16;
using u16x8  = __attribute__((ext_vector_type(8))) unsigned short;
using u8x8   = __attribute__((ext_vector_type(8))) unsigned char;
using f32x4  = __attribute__((ext_vector_type(4))) float;

#define NB 8
#define SEQ 2048
#define DIM 1024
#define MTOT (NB * SEQ)          // 16384

__device__ __forceinline__ unsigned short f2bf(float f) {
    unsigned int u = __float_as_uint(f);
    u = u + 0x7FFFu + ((u >> 16) & 1u);   // RNE
    return (unsigned short)(u >> 16);
}
__device__ __forceinline__ float bf2f(unsigned short h) {
    return __uint_as_float(((unsigned int)h) << 16);
}
// fp8 e4m3fn, non-negative values only; flush < 2^-6 to 0 (softmax-negligible)
__device__ __forceinline__ unsigned char f2e4m3(float f) {
    unsigned int u = __float_as_uint(f);
    u += 0x7FFFFu + ((u >> 20) & 1u);     // RNE into 3-bit mantissa
    int e = (int)(u >> 23) - 127;
    if (e < -6) return 0;
    return (unsigned char)(((e + 7) << 3) | ((u >> 20) & 7));
}
__device__ __forceinline__ float e4m3f(unsigned char b) {
    unsigned int e = b >> 3, m = b & 7;
    return e ? __uint_as_float(((e + 120u) << 23) | (m << 20)) : 0.f;
}

__device__ __forceinline__ void async16(const unsigned short* g, unsigned short* l) {
    __builtin_amdgcn_global_load_lds(
        (const __attribute__((address_space(1))) void*)g,
        (__attribute__((address_space(3))) void*)l, 16, 0, 0);
}

// ---------------- K1: u[i] = sum_j Wk[i,j] * bq[j]  (fp32) ----------------
__global__ __launch_bounds__(256) void k_u(const float* __restrict__ Wk,
                                           const float* __restrict__ bq,
                                           float* __restrict__ u) {
    const int wave = threadIdx.x >> 6, lane = threadIdx.x & 63;
    const int row = blockIdx.x * 4 + wave;
    const float* wr = Wk + (size_t)row * DIM;
    float s = 0.f;
#pragma unroll
    for (int p = 0; p < 4; ++p) {
        int col = p * 256 + lane * 4;
        float4 v = *reinterpret_cast<const float4*>(wr + col);
        float4 b = *reinterpret_cast<const float4*>(bq + col);
        s += v.x * b.x + v.y * b.y + v.z * b.z + v.w * b.w;
    }
#pragma unroll
    for (int off = 32; off; off >>= 1) s += __shfl_xor(s, off);
    if (lane == 0) u[row] = s;
}

// ---------------- K2: Wk,Wq fp32 -> bf16 ----------------
__global__ __launch_bounds__(256) void k_cvt_w(const float* __restrict__ Wk,
                                               const float* __restrict__ Wq,
                                               unsigned short* __restrict__ wkb,
                                               unsigned short* __restrict__ wqb) {
    const float* src = blockIdx.y ? Wq : Wk;
    unsigned short* dst = blockIdx.y ? wqb : wkb;
    size_t i = ((size_t)blockIdx.x * 256 + threadIdx.x) * 4;
    float4 v = *reinterpret_cast<const float4*>(src + i);
    ushort4 o;
    o.x = f2bf(v.x); o.y = f2bf(v.y); o.z = f2bf(v.z); o.w = f2bf(v.w);
    *reinterpret_cast<ushort4*>(dst + i) = o;
}

// ---------------- K3: x fp32 -> bf16, fused c[row] = scale * x[row].u ----------------
__global__ __launch_bounds__(256) void k_cvt_x(const float* __restrict__ x,
                                               const float* __restrict__ u,
                                               unsigned short* __restrict__ xb,
                                               float* __restrict__ c) {
    __shared__ float red[4];
    const int row = blockIdx.x, tid = threadIdx.x;
    size_t i = (size_t)row * DIM + tid * 4;
    float4 v = *reinterpret_cast<const float4*>(x + i);
    ushort4 o;
    o.x = f2bf(v.x); o.y = f2bf(v.y); o.z = f2bf(v.z); o.w = f2bf(v.w);
    *reinterpret_cast<ushort4*>(xb + i) = o;
    float4 uv = *reinterpret_cast<const float4*>(u + tid * 4);
    float s = v.x * uv.x + v.y * uv.y + v.z * uv.z + v.w * uv.w;
#pragma unroll
    for (int off = 32; off; off >>= 1) s += __shfl_xor(s, off);
    if ((tid & 63) == 0) red[tid >> 6] = s;
    __syncthreads();
    if (tid == 0) c[row] = 0.03125f * (red[0] + red[1] + red[2] + red[3]);
}

// ---------------- 128x128 tile GEMM, K-range (for Mt = Wk Wq^T) ----------------
__device__ __forceinline__ void gemm_bt_tile128(const unsigned short* __restrict__ A,
                                                const unsigned short* __restrict__ Bt,
                                                int kbeg, int kend, int m0, int n0,
                                                int lda, int ldb,
                                                unsigned short* ldsA, unsigned short* ldsB,
                                                f32x4 acc[4][4]) {
    const int tid  = threadIdx.x;
    const int wave = tid >> 6;
    const int lane = tid & 63;
    const int lrow = lane >> 3;
    const int lcol = lane & 7;
    const int wm = (wave >> 1) * 64;
    const int wn = (wave & 1) * 64;
    const int fr = lane & 15;
    const int fg = lane >> 4;

    for (int k0 = kbeg; k0 < kend; k0 += 64) {
#pragma unroll
        for (int r = 0; r < 4; ++r) {
            int row = r * 32 + wave * 8 + lrow;
            async16(A + (size_t)(m0 + row) * lda + k0 + lcol * 8, ldsA + r * 2048 + wave * 512);
            async16(Bt + (size_t)(n0 + row) * ldb + k0 + lcol * 8, ldsB + r * 2048 + wave * 512);
        }
        __syncthreads();
#pragma unroll
        for (int ks = 0; ks < 2; ++ks) {
            bf16x8 af[4], bfr[4];
#pragma unroll
            for (int mf = 0; mf < 4; ++mf)
                af[mf] = *reinterpret_cast<const bf16x8*>(ldsA + (wm + mf * 16 + fr) * 64 + ks * 32 + fg * 8);
#pragma unroll
            for (int nf = 0; nf < 4; ++nf)
                bfr[nf] = *reinterpret_cast<const bf16x8*>(ldsB + (wn + nf * 16 + fr) * 64 + ks * 32 + fg * 8);
#pragma unroll
            for (int mf = 0; mf < 4; ++mf)
#pragma unroll
                for (int nf = 0; nf < 4; ++nf)
                    acc[mf][nf] = __builtin_amdgcn_mfma_f32_16x16x32_bf16(af[mf], bfr[nf], acc[mf][nf], 0, 0, 0);
        }
        __syncthreads();
    }
}

// ---------------- K4: Mf += Wk @ Wq^T partial (K-split x4, fp32 atomics) ----------------
__global__ __launch_bounds__(256) void k_mm(const unsigned short* __restrict__ wkb,
                                            const unsigned short* __restrict__ wqb,
                                            float* __restrict__ Mf) {
    __shared__ unsigned short ldsA[128 * 64];
    __shared__ unsigned short ldsB[128 * 64];
    int m0 = blockIdx.x * 128, n0 = blockIdx.y * 128;
    int kz = blockIdx.z;
    f32x4 acc[4][4] = {};
    gemm_bt_tile128(wkb, wqb, kz * 256, kz * 256 + 256, m0, n0, DIM, DIM, ldsA, ldsB, acc);
    const int lane = threadIdx.x & 63, wave = threadIdx.x >> 6;
    const int wm = (wave >> 1) * 64, wn = (wave & 1) * 64;
    const int fr = lane & 15, fg = lane >> 4;
#pragma unroll
    for (int nf = 0; nf < 4; ++nf) {
        int n = n0 + wn + nf * 16 + fr;
#pragma unroll
        for (int mf = 0; mf < 4; ++mf) {
            int r0 = m0 + wm + mf * 16 + fg * 4;
#pragma unroll
            for (int j = 0; j < 4; ++j)
                atomicAdd(&Mf[(size_t)(r0 + j) * DIM + n], acc[mf][nf][j]);
        }
    }
}

// ---------------- K4b: Mf fp32 -> Mt bf16 ----------------
__global__ __launch_bounds__(256) void k_cvt_m(const float* __restrict__ Mf,
                                               unsigned short* __restrict__ Mt) {
    size_t i = ((size_t)blockIdx.x * 256 + threadIdx.x) * 4;
    float4 v = *reinterpret_cast<const float4*>(Mf + i);
    ushort4 o;
    o.x = f2bf(v.x); o.y = f2bf(v.y); o.z = f2bf(v.z); o.w = f2bf(v.w);
    *reinterpret_cast<ushort4*>(Mt + i) = o;
}

// ---------------------------------------------------------------------------
// 256x256 GEMM core (R5 best-measured variant). K = 1024.
// LDS[r][s16] = G[r][s16 ^ (r&7)]; FRAG XORs back. 1 barrier/phase.
// ---------------------------------------------------------------------------

#define STAGE(gbase, ld, dstoff)                                          \
    do {                                                                  \
        async16((gbase), ldsw + (dstoff));                                \
        async16((gbase) + 8 * (size_t)(ld), ldsw + (dstoff) + 512);       \
    } while (0)
#define STAGE_A(buf, half, kt) STAGE(gA + (size_t)((half) * 128) * lda + (kt) * 64, lda, (buf) * 16384 + (half) * 8192)
#define STAGE_B(buf, half, kt) STAGE(gB + (size_t)((half) * 128) * ldb + (kt) * 64, ldb, 32768 + (buf) * 16384 + (half) * 8192)

#define FRAG(base_us, row, colb) \
    (*(const bf16x8*)((const char*)(lds + (base_us)) + (row) * 128 + ((colb) ^ (((row) & 7) << 4))))

#define READ_A(dbuf, mh)                                                      \
    _Pragma("unroll") for (int m2 = 0; m2 < 4; ++m2) {                        \
        int arow = ((mh) * 4 + m2) * 16 + fr;                                 \
        _Pragma("unroll") for (int ks = 0; ks < 2; ++ks)                      \
            afc[(mh) * 4 + m2][ks] =                                          \
                FRAG((dbuf) * 16384 + wr * 8192, arow, ks * 64 + fg * 16);    \
    }
#define READ_B(dbuf, nh)                                                      \
    _Pragma("unroll") for (int n2 = 0; n2 < 2; ++n2) {                        \
        int brow = (wc & 1) * 64 + ((nh) * 2 + n2) * 16 + fr;                 \
        _Pragma("unroll") for (int ks = 0; ks < 2; ++ks)                      \
            bfc[nh][n2][ks] =                                                 \
                FRAG(32768 + (dbuf) * 16384 + (wc >> 1) * 8192, brow,         \
                     ks * 64 + fg * 16);                                      \
    }

#define VM4 asm volatile("s_waitcnt vmcnt(4)" ::: "memory")

#define PHASE(mh, nh, STG, VM, PF)                                            \
    do {                                                                      \
        STG;                                                                  \
        VM;                                                                   \
        asm volatile("s_barrier" ::: "memory");                               \
        asm volatile("s_waitcnt lgkmcnt(0)" ::: "memory");                    \
        __builtin_amdgcn_sched_barrier(0);                                    \
        PF;                                                                   \
        __builtin_amdgcn_sched_barrier(0);                                    \
        __builtin_amdgcn_s_setprio(1);                                        \
        _Pragma("unroll") for (int m2 = 0; m2 < 4; ++m2)                      \
            _Pragma("unroll") for (int n2 = 0; n2 < 2; ++n2) {                \
                f32x4& a = acc[(mh) * 4 + m2][(nh) * 2 + n2];                 \
                a = __builtin_amdgcn_mfma_f32_16x16x32_bf16(                  \
                    afc[(mh) * 4 + m2][0], bfc[nh][n2][0], a, 0, 0, 0);       \
                a = __builtin_amdgcn_mfma_f32_16x16x32_bf16(                  \
                    afc[(mh) * 4 + m2][1], bfc[nh][n2][1], a, 0, 0, 0);       \
            }                                                                 \
        __builtin_amdgcn_s_setprio(0);                                        \
    } while (0)

__device__ __forceinline__ void gemm256(const unsigned short* __restrict__ A,
                                        const unsigned short* __restrict__ Bt,
                                        int lda, int ldb, int m0, int n0,
                                        unsigned short* lds, f32x4 (&acc)[8][4]) {
    constexpr int NKT = 1024 / 64;   // 16 K-tiles
    constexpr int NIT = NKT / 2;     // 8 iterations
    const int tid = threadIdx.x;
    const int w = tid >> 6, lane = tid & 63;
    const int wr = w >> 2, wc = w & 3;
    const int fr = lane & 15, fg = lane >> 4;
    const int r8 = lane >> 3, slot = (lane & 7) ^ r8;

    const unsigned short* gA = A + (size_t)(m0 + w * 16 + r8) * lda + slot * 8;
    const unsigned short* gB = Bt + (size_t)(n0 + w * 16 + r8) * ldb + slot * 8;
    unsigned short* ldsw = lds + w * 1024;

    bf16x8 afc[8][2];
    bf16x8 bfc[2][2][2];

    STAGE_A(0, 0, 0); STAGE_A(0, 1, 0); STAGE_B(0, 0, 0); STAGE_B(0, 1, 0);
    STAGE_A(1, 0, 1); STAGE_A(1, 1, 1);
    VM4;
    asm volatile("s_barrier" ::: "memory");
    READ_A(0, 0); READ_B(0, 0);

    for (int it = 0; it < NIT; ++it) {
        const int t1 = 2 * it + 1;
        const int ka = (2 * it + 2) & (NKT - 1);
        const int kb = (2 * it + 3) & (NKT - 1);
        PHASE(0, 0, STAGE_B(1, 0, t1), , READ_A(0, 1));
        PHASE(1, 0, STAGE_B(1, 1, t1), , READ_B(0, 1));
        PHASE(0, 1, STAGE_A(0, 0, ka), , );
        PHASE(1, 1, STAGE_A(0, 1, ka), VM4, READ_A(1, 0); READ_B(1, 0));
        PHASE(0, 0, STAGE_B(0, 0, ka), , READ_A(1, 1));
        PHASE(1, 0, STAGE_B(0, 1, ka), , READ_B(1, 1));
        PHASE(0, 1, STAGE_A(1, 0, kb), , );
        PHASE(1, 1, STAGE_A(1, 1, kb), VM4, READ_A(0, 0); READ_B(0, 0));
    }
    asm volatile("s_waitcnt vmcnt(0) lgkmcnt(0)" ::: "memory");
}

// ---------------- K5: y = xb @ Mt^T (bf16) ----------------
__global__ __launch_bounds__(512, 2) void k_proj_y(const unsigned short* __restrict__ xb,
                                                   const unsigned short* __restrict__ Mt,
                                                   unsigned short* __restrict__ y) {
    __shared__ unsigned short lds[65536];   // 128 KiB
    const int f = blockIdx.x;
    const int m_hi = f & 7, j = f >> 3;
    const int n_t = j & 3, m_lo = j >> 2;
    const int m0 = (m_hi * 8 + m_lo) * 256, n0 = n_t * 256;

    f32x4 acc[8][4] = {};
    gemm256(xb, Mt, DIM, DIM, m0, n0, lds, acc);

    const int tid = threadIdx.x, w = tid >> 6, lane = tid & 63;
    const int wr = w >> 2, wc = w & 3, fr = lane & 15, fg = lane >> 4;
#pragma unroll
    for (int nf = 0; nf < 4; ++nf) {
        int n = n0 + wc * 64 + nf * 16 + fr;
#pragma unroll
        for (int mf = 0; mf < 8; ++mf) {
            int r0 = m0 + wr * 128 + mf * 16 + fg * 4;
#pragma unroll
            for (int j2 = 0; j2 < 4; ++j2)
                y[(size_t)(r0 + j2) * DIM + n] = f2bf(acc[mf][nf][j2]);
        }
    }
}

// ---------------- K6: P = exp(y x^T * scale + c[t]) fp8, ell = rowsum ----------------
__global__ __launch_bounds__(512, 2) void k_scores(const unsigned short* __restrict__ y,
                                                   const unsigned short* __restrict__ xb,
                                                   const float* __restrict__ c,
                                                   unsigned char* __restrict__ P,
                                                   float* __restrict__ ell) {
    __shared__ unsigned short lds[65536];
    const int f = blockIdx.x;
    const int b = f & 7, j = f >> 3;
    const int mt = j & 7, nt = j >> 3;
    const unsigned short* q = y + (size_t)b * SEQ * DIM;
    const unsigned short* k = xb + (size_t)b * SEQ * DIM;
    const int m0 = mt * 256, n0 = nt * 256;

    f32x4 acc[8][4] = {};
    gemm256(q, k, DIM, DIM, m0, n0, lds, acc);

    const float scale = 0.03125f;  // 1/sqrt(1024)
    const int tid = threadIdx.x, w = tid >> 6, lane = tid & 63;
    const int wr = w >> 2, wc = w & 3, fr = lane & 15, fg = lane >> 4;
    unsigned char* Pb = P + (size_t)b * SEQ * SEQ;
    float cv[4];
#pragma unroll
    for (int nf = 0; nf < 4; ++nf)
        cv[nf] = c[(size_t)b * SEQ + n0 + wc * 64 + nf * 16 + fr];
#pragma unroll
    for (int mf = 0; mf < 8; ++mf) {
#pragma unroll
        for (int j2 = 0; j2 < 4; ++j2) {
            int s = m0 + wr * 128 + mf * 16 + fg * 4 + j2;
            float rs = 0.f;
#pragma unroll
            for (int nf = 0; nf < 4; ++nf) {
                int t = n0 + wc * 64 + nf * 16 + fr;
                float p = __expf(acc[mf][nf][j2] * scale + cv[nf]);
                unsigned char pu = f2e4m3(p);
                Pb[(size_t)s * SEQ + t] = pu;
                rs += e4m3f(pu);  // ell consistent with stored fp8 P
            }
            rs += __shfl_xor(rs, 1);
            rs += __shfl_xor(rs, 2);
            rs += __shfl_xor(rs, 4);
            rs += __shfl_xor(rs, 8);
            if (fr == 0) atomicAdd(&ell[b * SEQ + s], rs);
        }
    }
}

// ---------------- K7: w[b,t] = sum_s P[b,s,t] / ell[b,s]  (8 cols/thread) ----------------
__global__ __launch_bounds__(256) void k_colsum(const unsigned char* __restrict__ P,
                                                const float* __restrict__ ell,
                                                float* __restrict__ w) {
    int b = blockIdx.z;
    int t8 = threadIdx.x * 8;
    int s0 = blockIdx.y * 64;
    const unsigned char* Pb = P + (size_t)b * SEQ * SEQ;
    const float* eb = ell + b * SEQ;
    float a[8] = {};
    for (int s = s0; s < s0 + 64; ++s) {
        u8x8 pv = *reinterpret_cast<const u8x8*>(Pb + (size_t)s * SEQ + t8);
        float re = 1.0f / eb[s];
#pragma unroll
        for (int j = 0; j < 8; ++j) a[j] += e4m3f(pv[j]) * re;
    }
#pragma unroll
    for (int j = 0; j < 8; ++j) atomicAdd(&w[b * SEQ + t8 + j], a[j]);
}

// ---------------- K8: g[b,d] = (1/S) sum_t w[b,t] * xb[b,t,d] ----------------
__global__ __launch_bounds__(256) void k_accx(const float* __restrict__ w,
                                              const unsigned short* __restrict__ xb,
                                              float* __restrict__ g) {
    int b = blockIdx.z;
    int d = blockIdx.x * 256 + threadIdx.x;
    int t0 = blockIdx.y * 256;
    const unsigned short* xbb = xb + (size_t)b * SEQ * DIM;
    const float* wb = w + b * SEQ;
    float acc = 0.f;
    for (int t = t0; t < t0 + 256; ++t)
        acc += wb[t] * bf2f(xbb[(size_t)t * DIM + d]);
    atomicAdd(&g[b * DIM + d], acc * (1.0f / (float)SEQ));
}

// ---------------- K9a: out[b,n] = bv[n] ----------------
__global__ __launch_bounds__(256) void k_init_out(const float* __restrict__ bv,
                                                  float* __restrict__ out) {
    int i = blockIdx.x * 256 + threadIdx.x;
    out[i] = bv[i & (DIM - 1)];
}

// ---------------- K9b: out[b,n] += sum_{d in chunk} g[b,d] * Wv[d,n] ----------------
__global__ __launch_bounds__(256) void k_out2(const float* __restrict__ g,
                                              const float* __restrict__ Wv,
                                              float* __restrict__ out) {
    int b = blockIdx.y;
    int n = blockIdx.x * 256 + threadIdx.x;
    int d0 = blockIdx.z * 64;
    const float* gb = g + b * DIM;
    float acc = 0.f;
#pragma unroll
    for (int d = 0; d < 64; ++d)
        acc += gb[d0 + d] * Wv[(size_t)(d0 + d) * DIM + n];
    atomicAdd(&out[b * DIM + n], acc);
}

extern "C" void kernel_launch(void* const* d_in, const int* in_sizes, int n_in,
                              void* d_out, int out_size, void* d_ws, size_t ws_size,
                              hipStream_t stream) {
    const float* x  = (const float*)d_in[0];
    const float* Wq = (const float*)d_in[1];
    const float* bq = (const float*)d_in[2];
    const float* Wk = (const float*)d_in[3];
    const float* bk = (const float*)d_in[4];   // unused (softmax-invariant)
    const float* Wv = (const float*)d_in[5];
    const float* bv = (const float*)d_in[6];
    float* out = (float*)d_out;
    (void)bk;

    char* ws = (char*)d_ws;
    unsigned short* xb  = (unsigned short*)(ws);                    //  33,554,432
    unsigned short* wkb = (unsigned short*)(ws + 33554432ull);      //   2,097,152
    unsigned short* wqb = (unsigned short*)(ws + 35651584ull);      //   2,097,152
    unsigned short* Mt  = (unsigned short*)(ws + 37748736ull);      //   2,097,152
    unsigned short* y   = (unsigned short*)(ws + 39845888ull);      //  33,554,432
    unsigned char*  P   = (unsigned char*)(ws + 73400320ull);       //  33,554,432 (fp8)
    float*          Mf  = (float*)(ws + 106954752ull);              //   4,194,304
    float*          ell = (float*)(ws + 111149056ull);              //      65,536
    float*          w   = (float*)(ws + 111214592ull);              //      65,536
    float*          c   = (float*)(ws + 111280128ull);              //      65,536
    float*          u   = (float*)(ws + 111345664ull);              //       4,096
    float*          g   = (float*)(ws + 111349760ull);              //      32,768

    hipMemsetAsync(ell, 0, SEQ * NB * sizeof(float), stream);
    hipMemsetAsync(w,   0, SEQ * NB * sizeof(float), stream);
    hipMemsetAsync(g,   0, DIM * NB * sizeof(float), stream);
    hipMemsetAsync(Mf,  0, (size_t)DIM * DIM * sizeof(float), stream);

    k_u<<<dim3(DIM / 4), 256, 0, stream>>>(Wk, bq, u);
    k_cvt_w<<<dim3(DIM * DIM / 4 / 256, 2), 256, 0, stream>>>(Wk, Wq, wkb, wqb);
    k_init_out<<<dim3(NB * DIM / 256), 256, 0, stream>>>(bv, out);
    k_cvt_x<<<dim3(MTOT), 256, 0, stream>>>(x, u, xb, c);
    k_mm<<<dim3(8, 8, 4), 256, 0, stream>>>(wkb, wqb, Mf);
    k_cvt_m<<<dim3(DIM * DIM / 4 / 256), 256, 0, stream>>>(Mf, Mt);
    k_proj_y<<<dim3(256), 512, 0, stream>>>(xb, Mt, y);
    k_scores<<<dim3(512), 512, 0, stream>>>(y, xb, c, P, ell);
    k_colsum<<<dim3(1, SEQ / 64, NB), 256, 0, stream>>>(P, ell, w);
    k_accx<<<dim3(DIM / 256, SEQ / 256, NB), 256, 0, stream>>>(w, xb, g);
    k_out2<<<dim3(DIM / 256, NB, 16), 256, 0, stream>>>(g, Wv, out);
}

// Round 10
// 206.626 us; speedup vs baseline: 1.1363x; 1.1363x over previous
//
#include <hip/hip_runtime.h>

// ---------------------------------------------------------------------------
// AttentionFuse: out[b,d] = mean_s( softmax((x Wq + bq)(x Wk + bk)^T / 32) @ (x Wv + bv) )
// Algebra:
//   mean_s(attn @ V) = sum_t a[t] V[t,:]  =>  out = (a^T x) Wv + bv   (V GEMM gone)
//   S = x (Wq Wk^T) x^T  =>  y = x Mt^T, Mt = Wk Wq^T (2.1 GF)  =>  S = y x^T
//   bias: P[s,t] = exp(scale*S + c[t]),  c[t] = scale * x[t].u,  u = Wk bq
// R10: k_mm atomics reverted (R9 regression); fp8 via HW cvt builtins;
//   P stored TRANSPOSED (PT[t][s]) -> dword stores + contiguous colsum reads;
//   k_accx 16B loads; prep kernels merged; single memset. 9 graph nodes.
// ---------------------------------------------------------------------------

using bf16x8 = __attribute__((ext_vector_type(8))) __bf16;
using u16x8  = __attribute__((ext_vector_type(8))) unsigned short;
using f32x4  = __attribute__((ext_vector_type(4))) float;
using f32x2  = __attribute__((ext_vector_type(2))) float;

#define NB 8
#define SEQ 2048
#define DIM 1024
#define MTOT (NB * SEQ)          // 16384

__device__ __forceinline__ unsigned short f2bf(float f) {
    unsigned int u = __float_as_uint(f);
    u = u + 0x7FFFu + ((u >> 16) & 1u);   // RNE
    return (unsigned short)(u >> 16);
}
__device__ __forceinline__ float bf2f(unsigned short h) {
    return __uint_as_float(((unsigned int)h) << 16);
}

__device__ __forceinline__ void async16(const unsigned short* g, unsigned short* l) {
    __builtin_amdgcn_global_load_lds(
        (const __attribute__((address_space(1))) void*)g,
        (__attribute__((address_space(3))) void*)l, 16, 0, 0);
}

// ---------------- K0 (merged prep): cvt_w x2, u = Wk bq, out = bv ----------------
__global__ __launch_bounds__(256) void k_prep(const float* __restrict__ Wk,
                                              const float* __restrict__ Wq,
                                              const float* __restrict__ bq,
                                              const float* __restrict__ bv,
                                              unsigned short* __restrict__ wkb,
                                              unsigned short* __restrict__ wqb,
                                              float* __restrict__ u,
                                              float* __restrict__ out) {
    const int bid = blockIdx.x;
    if (bid < 2048) {                       // Wk,Wq fp32 -> bf16
        const float* src = (bid >= 1024) ? Wq : Wk;
        unsigned short* dst = (bid >= 1024) ? wqb : wkb;
        size_t i = ((size_t)(bid & 1023) * 256 + threadIdx.x) * 4;
        float4 v = *reinterpret_cast<const float4*>(src + i);
        ushort4 o;
        o.x = f2bf(v.x); o.y = f2bf(v.y); o.z = f2bf(v.z); o.w = f2bf(v.w);
        *reinterpret_cast<ushort4*>(dst + i) = o;
    } else if (bid < 2304) {                // u[row] = Wk[row,:].bq
        const int wave = threadIdx.x >> 6, lane = threadIdx.x & 63;
        const int row = (bid - 2048) * 4 + wave;
        const float* wr = Wk + (size_t)row * DIM;
        float s = 0.f;
#pragma unroll
        for (int p = 0; p < 4; ++p) {
            int col = p * 256 + lane * 4;
            float4 v = *reinterpret_cast<const float4*>(wr + col);
            float4 b = *reinterpret_cast<const float4*>(bq + col);
            s += v.x * b.x + v.y * b.y + v.z * b.z + v.w * b.w;
        }
#pragma unroll
        for (int off = 32; off; off >>= 1) s += __shfl_xor(s, off);
        if (lane == 0) u[row] = s;
    } else {                                // out[b,n] = bv[n]
        int i = (bid - 2304) * 256 + threadIdx.x;
        out[i] = bv[i & (DIM - 1)];
    }
}

// ---------------- K1: x fp32 -> bf16, fused c[row] = scale * x[row].u ----------------
__global__ __launch_bounds__(256) void k_cvt_x(const float* __restrict__ x,
                                               const float* __restrict__ u,
                                               unsigned short* __restrict__ xb,
                                               float* __restrict__ c) {
    __shared__ float red[4];
    const int row = blockIdx.x, tid = threadIdx.x;
    size_t i = (size_t)row * DIM + tid * 4;
    float4 v = *reinterpret_cast<const float4*>(x + i);
    ushort4 o;
    o.x = f2bf(v.x); o.y = f2bf(v.y); o.z = f2bf(v.z); o.w = f2bf(v.w);
    *reinterpret_cast<ushort4*>(xb + i) = o;
    float4 uv = *reinterpret_cast<const float4*>(u + tid * 4);
    float s = v.x * uv.x + v.y * uv.y + v.z * uv.z + v.w * uv.w;
#pragma unroll
    for (int off = 32; off; off >>= 1) s += __shfl_xor(s, off);
    if ((tid & 63) == 0) red[tid >> 6] = s;
    __syncthreads();
    if (tid == 0) c[row] = 0.03125f * (red[0] + red[1] + red[2] + red[3]);
}

// ---------------- 128x128 tile GEMM (for Mt = Wk Wq^T) ----------------
__device__ __forceinline__ void gemm_bt_tile128(const unsigned short* __restrict__ A,
                                                const unsigned short* __restrict__ Bt,
                                                int K, int m0, int n0, int lda, int ldb,
                                                unsigned short* ldsA, unsigned short* ldsB,
                                                f32x4 acc[4][4]) {
    const int tid  = threadIdx.x;
    const int wave = tid >> 6;
    const int lane = tid & 63;
    const int lrow = lane >> 3;
    const int lcol = lane & 7;
    const int wm = (wave >> 1) * 64;
    const int wn = (wave & 1) * 64;
    const int fr = lane & 15;
    const int fg = lane >> 4;

    for (int k0 = 0; k0 < K; k0 += 64) {
#pragma unroll
        for (int r = 0; r < 4; ++r) {
            int row = r * 32 + wave * 8 + lrow;
            async16(A + (size_t)(m0 + row) * lda + k0 + lcol * 8, ldsA + r * 2048 + wave * 512);
            async16(Bt + (size_t)(n0 + row) * ldb + k0 + lcol * 8, ldsB + r * 2048 + wave * 512);
        }
        __syncthreads();
#pragma unroll
        for (int ks = 0; ks < 2; ++ks) {
            bf16x8 af[4], bfr[4];
#pragma unroll
            for (int mf = 0; mf < 4; ++mf)
                af[mf] = *reinterpret_cast<const bf16x8*>(ldsA + (wm + mf * 16 + fr) * 64 + ks * 32 + fg * 8);
#pragma unroll
            for (int nf = 0; nf < 4; ++nf)
                bfr[nf] = *reinterpret_cast<const bf16x8*>(ldsB + (wn + nf * 16 + fr) * 64 + ks * 32 + fg * 8);
#pragma unroll
            for (int mf = 0; mf < 4; ++mf)
#pragma unroll
                for (int nf = 0; nf < 4; ++nf)
                    acc[mf][nf] = __builtin_amdgcn_mfma_f32_16x16x32_bf16(af[mf], bfr[nf], acc[mf][nf], 0, 0, 0);
        }
        __syncthreads();
    }
}

// ---------------- K2: Mt = Wk @ Wq^T (bf16) ----------------
__global__ __launch_bounds__(256) void k_mm(const unsigned short* __restrict__ wkb,
                                            const unsigned short* __restrict__ wqb,
                                            unsigned short* __restrict__ Mt) {
    __shared__ unsigned short ldsA[128 * 64];
    __shared__ unsigned short ldsB[128 * 64];
    int m0 = blockIdx.x * 128, n0 = blockIdx.y * 128;
    f32x4 acc[4][4] = {};
    gemm_bt_tile128(wkb, wqb, DIM, m0, n0, DIM, DIM, ldsA, ldsB, acc);
    const int lane = threadIdx.x & 63, wave = threadIdx.x >> 6;
    const int wm = (wave >> 1) * 64, wn = (wave & 1) * 64;
    const int fr = lane & 15, fg = lane >> 4;
#pragma unroll
    for (int nf = 0; nf < 4; ++nf) {
        int n = n0 + wn + nf * 16 + fr;
#pragma unroll
        for (int mf = 0; mf < 4; ++mf) {
            int r0 = m0 + wm + mf * 16 + fg * 4;
#pragma unroll
            for (int j = 0; j < 4; ++j)
                Mt[(size_t)(r0 + j) * DIM + n] = f2bf(acc[mf][nf][j]);
        }
    }
}

// ---------------------------------------------------------------------------
// 256x256 GEMM core (R5 best-measured variant). K = 1024.
// LDS[r][s16] = G[r][s16 ^ (r&7)]; FRAG XORs back. 1 barrier/phase.
// ---------------------------------------------------------------------------

#define STAGE(gbase, ld, dstoff)                                          \
    do {                                                                  \
        async16((gbase), ldsw + (dstoff));                                \
        async16((gbase) + 8 * (size_t)(ld), ldsw + (dstoff) + 512);       \
    } while (0)
#define STAGE_A(buf, half, kt) STAGE(gA + (size_t)((half) * 128) * lda + (kt) * 64, lda, (buf) * 16384 + (half) * 8192)
#define STAGE_B(buf, half, kt) STAGE(gB + (size_t)((half) * 128) * ldb + (kt) * 64, ldb, 32768 + (buf) * 16384 + (half) * 8192)

#define FRAG(base_us, row, colb) \
    (*(const bf16x8*)((const char*)(lds + (base_us)) + (row) * 128 + ((colb) ^ (((row) & 7) << 4))))

#define READ_A(dbuf, mh)                                                      \
    _Pragma("unroll") for (int m2 = 0; m2 < 4; ++m2) {                        \
        int arow = ((mh) * 4 + m2) * 16 + fr;                                 \
        _Pragma("unroll") for (int ks = 0; ks < 2; ++ks)                      \
            afc[(mh) * 4 + m2][ks] =                                          \
                FRAG((dbuf) * 16384 + wr * 8192, arow, ks * 64 + fg * 16);    \
    }
#define READ_B(dbuf, nh)                                                      \
    _Pragma("unroll") for (int n2 = 0; n2 < 2; ++n2) {                        \
        int brow = (wc & 1) * 64 + ((nh) * 2 + n2) * 16 + fr;                 \
        _Pragma("unroll") for (int ks = 0; ks < 2; ++ks)                      \
            bfc[nh][n2][ks] =                                                 \
                FRAG(32768 + (dbuf) * 16384 + (wc >> 1) * 8192, brow,         \
                     ks * 64 + fg * 16);                                      \
    }

#define VM4 asm volatile("s_waitcnt vmcnt(4)" ::: "memory")

#define PHASE(mh, nh, STG, VM, PF)                                            \
    do {                                                                      \
        STG;                                                                  \
        VM;                                                                   \
        asm volatile("s_barrier" ::: "memory");                               \
        asm volatile("s_waitcnt lgkmcnt(0)" ::: "memory");                    \
        __builtin_amdgcn_sched_barrier(0);                                    \
        PF;                                                                   \
        __builtin_amdgcn_sched_barrier(0);                                    \
        __builtin_amdgcn_s_setprio(1);                                        \
        _Pragma("unroll") for (int m2 = 0; m2 < 4; ++m2)                      \
            _Pragma("unroll") for (int n2 = 0; n2 < 2; ++n2) {                \
                f32x4& a = acc[(mh) * 4 + m2][(nh) * 2 + n2];                 \
                a = __builtin_amdgcn_mfma_f32_16x16x32_bf16(                  \
                    afc[(mh) * 4 + m2][0], bfc[nh][n2][0], a, 0, 0, 0);       \
                a = __builtin_amdgcn_mfma_f32_16x16x32_bf16(                  \
                    afc[(mh) * 4 + m2][1], bfc[nh][n2][1], a, 0, 0, 0);       \
            }                                                                 \
        __builtin_amdgcn_s_setprio(0);                                        \
    } while (0)

__device__ __forceinline__ void gemm256(const unsigned short* __restrict__ A,
                                        const unsigned short* __restrict__ Bt,
                                        int lda, int ldb, int m0, int n0,
                                        unsigned short* lds, f32x4 (&acc)[8][4]) {
    constexpr int NKT = 1024 / 64;   // 16 K-tiles
    constexpr int NIT = NKT / 2;     // 8 iterations
    const int tid = threadIdx.x;
    const int w = tid >> 6, lane = tid & 63;
    const int wr = w >> 2, wc = w & 3;
    const int fr = lane & 15, fg = lane >> 4;
    const int r8 = lane >> 3, slot = (lane & 7) ^ r8;

    const unsigned short* gA = A + (size_t)(m0 + w * 16 + r8) * lda + slot * 8;
    const unsigned short* gB = Bt + (size_t)(n0 + w * 16 + r8) * ldb + slot * 8;
    unsigned short* ldsw = lds + w * 1024;

    bf16x8 afc[8][2];
    bf16x8 bfc[2][2][2];

    STAGE_A(0, 0, 0); STAGE_A(0, 1, 0); STAGE_B(0, 0, 0); STAGE_B(0, 1, 0);
    STAGE_A(1, 0, 1); STAGE_A(1, 1, 1);
    VM4;
    asm volatile("s_barrier" ::: "memory");
    READ_A(0, 0); READ_B(0, 0);

    for (int it = 0; it < NIT; ++it) {
        const int t1 = 2 * it + 1;
        const int ka = (2 * it + 2) & (NKT - 1);
        const int kb = (2 * it + 3) & (NKT - 1);
        PHASE(0, 0, STAGE_B(1, 0, t1), , READ_A(0, 1));
        PHASE(1, 0, STAGE_B(1, 1, t1), , READ_B(0, 1));
        PHASE(0, 1, STAGE_A(0, 0, ka), , );
        PHASE(1, 1, STAGE_A(0, 1, ka), VM4, READ_A(1, 0); READ_B(1, 0));
        PHASE(0, 0, STAGE_B(0, 0, ka), , READ_A(1, 1));
        PHASE(1, 0, STAGE_B(0, 1, ka), , READ_B(1, 1));
        PHASE(0, 1, STAGE_A(1, 0, kb), , );
        PHASE(1, 1, STAGE_A(1, 1, kb), VM4, READ_A(0, 0); READ_B(0, 0));
    }
    asm volatile("s_waitcnt vmcnt(0) lgkmcnt(0)" ::: "memory");
}

// ---------------- K3: y = xb @ Mt^T (bf16) ----------------
__global__ __launch_bounds__(512, 2) void k_proj_y(const unsigned short* __restrict__ xb,
                                                   const unsigned short* __restrict__ Mt,
                                                   unsigned short* __restrict__ y) {
    __shared__ unsigned short lds[65536];   // 128 KiB
    const int f = blockIdx.x;
    const int m_hi = f & 7, j = f >> 3;
    const int n_t = j & 3, m_lo = j >> 2;
    const int m0 = (m_hi * 8 + m_lo) * 256, n0 = n_t * 256;

    f32x4 acc[8][4] = {};
    gemm256(xb, Mt, DIM, DIM, m0, n0, lds, acc);

    const int tid = threadIdx.x, w = tid >> 6, lane = tid & 63;
    const int wr = w >> 2, wc = w & 3, fr = lane & 15, fg = lane >> 4;
#pragma unroll
    for (int nf = 0; nf < 4; ++nf) {
        int n = n0 + wc * 64 + nf * 16 + fr;
#pragma unroll
        for (int mf = 0; mf < 8; ++mf) {
            int r0 = m0 + wr * 128 + mf * 16 + fg * 4;
#pragma unroll
            for (int j2 = 0; j2 < 4; ++j2)
                y[(size_t)(r0 + j2) * DIM + n] = f2bf(acc[mf][nf][j2]);
        }
    }
}

// ---------------- K4: PT[t][s] = fp8(exp(S*scale + c[t])), ell[s] = rowsum ----------------
__global__ __launch_bounds__(512, 2) void k_scores(const unsigned short* __restrict__ y,
                                                   const unsigned short* __restrict__ xb,
                                                   const float* __restrict__ c,
                                                   unsigned char* __restrict__ PT,
                                                   float* __restrict__ ell) {
    __shared__ unsigned short lds[65536];
    const int f = blockIdx.x;
    const int b = f & 7, j = f >> 3;
    const int mt = j & 7, nt = j >> 3;
    const unsigned short* q = y + (size_t)b * SEQ * DIM;
    const unsigned short* k = xb + (size_t)b * SEQ * DIM;
    const int m0 = mt * 256, n0 = nt * 256;

    f32x4 acc[8][4] = {};
    gemm256(q, k, DIM, DIM, m0, n0, lds, acc);

    const float scl = 0.03125f;  // 1/sqrt(1024)
    const int tid = threadIdx.x, w = tid >> 6, lane = tid & 63;
    const int wr = w >> 2, wc = w & 3, fr = lane & 15, fg = lane >> 4;
    unsigned char* Pb = PT + (size_t)b * SEQ * SEQ;
    float cv[4];
#pragma unroll
    for (int nf = 0; nf < 4; ++nf)
        cv[nf] = c[(size_t)b * SEQ + n0 + wc * 64 + nf * 16 + fr];
#pragma unroll
    for (int mf = 0; mf < 8; ++mf) {
        const int sbase = m0 + wr * 128 + mf * 16 + fg * 4;
        float rs[4] = {0.f, 0.f, 0.f, 0.f};
#pragma unroll
        for (int nf = 0; nf < 4; ++nf) {
            int t = n0 + wc * 64 + nf * 16 + fr;
            float p0 = __expf(fmaf(acc[mf][nf][0], scl, cv[nf]));
            float p1 = __expf(fmaf(acc[mf][nf][1], scl, cv[nf]));
            float p2 = __expf(fmaf(acc[mf][nf][2], scl, cv[nf]));
            float p3 = __expf(fmaf(acc[mf][nf][3], scl, cv[nf]));
            int pk = __builtin_amdgcn_cvt_pk_fp8_f32(p0, p1, 0, false);
            pk = __builtin_amdgcn_cvt_pk_fp8_f32(p2, p3, pk, true);
            *reinterpret_cast<unsigned int*>(Pb + (size_t)t * SEQ + sbase) = (unsigned int)pk;
            f32x2 d01 = __builtin_amdgcn_cvt_pk_f32_fp8(pk, false);
            f32x2 d23 = __builtin_amdgcn_cvt_pk_f32_fp8(pk, true);
            rs[0] += d01[0]; rs[1] += d01[1]; rs[2] += d23[0]; rs[3] += d23[1];
        }
#pragma unroll
        for (int j2 = 0; j2 < 4; ++j2) {
            float r = rs[j2];
            r += __shfl_xor(r, 1);
            r += __shfl_xor(r, 2);
            r += __shfl_xor(r, 4);
            r += __shfl_xor(r, 8);
            if (fr == 0) atomicAdd(&ell[b * SEQ + sbase + j2], r);
        }
    }
}

// ---------------- K5: w[t] = sum_s PT[t][s] / ell[s]  (contig s-reads) ----------------
__global__ __launch_bounds__(256) void k_colsum(const unsigned char* __restrict__ PT,
                                                const float* __restrict__ ell,
                                                float* __restrict__ w) {
    __shared__ float rel[512];
    const int b = blockIdx.z;
    const int s0 = blockIdx.x * 512;
    const int t = blockIdx.y * 256 + threadIdx.x;
    {
        int i = threadIdx.x;
        rel[i]       = 1.0f / ell[b * SEQ + s0 + i];
        rel[i + 256] = 1.0f / ell[b * SEQ + s0 + 256 + i];
    }
    __syncthreads();
    const unsigned char* Pt = PT + (size_t)b * SEQ * SEQ + (size_t)t * SEQ + s0;
    float a = 0.f;
    for (int i = 0; i < 512; i += 8) {
        uint2 pv = *reinterpret_cast<const uint2*>(Pt + i);
        f32x2 d0 = __builtin_amdgcn_cvt_pk_f32_fp8((int)pv.x, false);
        f32x2 d1 = __builtin_amdgcn_cvt_pk_f32_fp8((int)pv.x, true);
        f32x2 d2 = __builtin_amdgcn_cvt_pk_f32_fp8((int)pv.y, false);
        f32x2 d3 = __builtin_amdgcn_cvt_pk_f32_fp8((int)pv.y, true);
        a += d0[0] * rel[i]     + d0[1] * rel[i + 1] + d1[0] * rel[i + 2] + d1[1] * rel[i + 3];
        a += d2[0] * rel[i + 4] + d2[1] * rel[i + 5] + d3[0] * rel[i + 6] + d3[1] * rel[i + 7];
    }
    atomicAdd(&w[b * SEQ + t], a);
}

// ---------------- K6: g[b,d] = (1/S) sum_t w[b,t] * xb[b,t,d]  (16B loads) ----------------
__global__ __launch_bounds__(256) void k_accx(const float* __restrict__ w,
                                              const unsigned short* __restrict__ xb,
                                              float* __restrict__ g) {
    const int b = blockIdx.y;
    const int t0 = blockIdx.x * 64 + (threadIdx.x >> 7) * 32;
    const int d8 = (threadIdx.x & 127) * 8;
    const unsigned short* xbb = xb + (size_t)b * SEQ * DIM;
    const float* wb = w + b * SEQ;
    float a[8] = {};
    for (int i = 0; i < 32; ++i) {
        int t = t0 + i;
        float wt = wb[t];
        u16x8 v = *reinterpret_cast<const u16x8*>(xbb + (size_t)t * DIM + d8);
#pragma unroll
        for (int j = 0; j < 8; ++j) a[j] += wt * bf2f(v[j]);
    }
#pragma unroll
    for (int j = 0; j < 8; ++j)
        atomicAdd(&g[b * DIM + d8 + j], a[j] * (1.0f / (float)SEQ));
}

// ---------------- K7: out[b,n] += sum_{d in chunk} g[b,d] * Wv[d,n] ----------------
__global__ __launch_bounds__(256) void k_out2(const float* __restrict__ g,
                                              const float* __restrict__ Wv,
                                              float* __restrict__ out) {
    int b = blockIdx.y;
    int n = blockIdx.x * 256 + threadIdx.x;
    int d0 = blockIdx.z * 64;
    const float* gb = g + b * DIM;
    float acc = 0.f;
#pragma unroll
    for (int d = 0; d < 64; ++d)
        acc += gb[d0 + d] * Wv[(size_t)(d0 + d) * DIM + n];
    atomicAdd(&out[b * DIM + n], acc);
}

extern "C" void kernel_launch(void* const* d_in, const int* in_sizes, int n_in,
                              void* d_out, int out_size, void* d_ws, size_t ws_size,
                              hipStream_t stream) {
    const float* x  = (const float*)d_in[0];
    const float* Wq = (const float*)d_in[1];
    const float* bq = (const float*)d_in[2];
    const float* Wk = (const float*)d_in[3];
    const float* bk = (const float*)d_in[4];   // unused (softmax-invariant)
    const float* Wv = (const float*)d_in[5];
    const float* bv = (const float*)d_in[6];
    float* out = (float*)d_out;
    (void)bk;

    char* ws = (char*)d_ws;
    unsigned short* xb  = (unsigned short*)(ws);                    //  33,554,432
    unsigned short* wkb = (unsigned short*)(ws + 33554432ull);      //   2,097,152
    unsigned short* wqb = (unsigned short*)(ws + 35651584ull);      //   2,097,152
    unsigned short* Mt  = (unsigned short*)(ws + 37748736ull);      //   2,097,152
    unsigned short* y   = (unsigned short*)(ws + 39845888ull);      //  33,554,432
    unsigned char*  PT  = (unsigned char*)(ws + 73400320ull);       //  33,554,432 (fp8, transposed)
    float*          ell = (float*)(ws + 106954752ull);              //      65,536
    float*          w   = (float*)(ws + 107020288ull);              //      65,536
    float*          g   = (float*)(ws + 107085824ull);              //      32,768
    float*          c   = (float*)(ws + 107118592ull);              //      65,536
    float*          u   = (float*)(ws + 107184128ull);              //       4,096

    // single memset: ell + w + g are contiguous (163,840 bytes)
    hipMemsetAsync(ell, 0, 163840, stream);

    k_prep<<<dim3(2336), 256, 0, stream>>>(Wk, Wq, bq, bv, wkb, wqb, u, out);
    k_cvt_x<<<dim3(MTOT), 256, 0, stream>>>(x, u, xb, c);
    k_mm<<<dim3(8, 8), 256, 0, stream>>>(wkb, wqb, Mt);
    k_proj_y<<<dim3(256), 512, 0, stream>>>(xb, Mt, y);
    k_scores<<<dim3(512), 512, 0, stream>>>(y, xb, c, PT, ell);
    k_colsum<<<dim3(SEQ / 512, SEQ / 256, NB), 256, 0, stream>>>(PT, ell, w);
    k_accx<<<dim3(SEQ / 64, NB), 256, 0, stream>>>(w, xb, g);
    k_out2<<<dim3(DIM / 256, NB, 16), 256, 0, stream>>>(g, Wv, out);
}